// Round 2
// baseline (148.448 us; speedup 1.0000x reference)
//
#include <hip/hip_runtime.h>
#include <hip/hip_bf16.h>
#include <stdint.h>

// ---------------- problem constants ----------------
#define BATCH 16
#define CDIM  1024
#define FWID  32
#define HW    1024
#define NA    1024
#define NTOT  (BATCH*NA)    // 16384
#define NCHUNK 16           // 8 m-blocks * 2 waves in N
#define MARGIN 0.6f

typedef __bf16 bf16x8 __attribute__((ext_vector_type(8)));
typedef float  f32x4  __attribute__((ext_vector_type(4)));
typedef unsigned short us4 __attribute__((ext_vector_type(4)));
typedef unsigned short us8 __attribute__((ext_vector_type(8)));
typedef float  f4     __attribute__((ext_vector_type(4)));

template<int OFF>
__device__ __forceinline__ us4 tr_read(uint32_t addr){
  us4 r;
  asm volatile("ds_read_b64_tr_b16 %0, %1 offset:%2" : "=v"(r) : "v"(addr), "n"(OFF));
  return r;
}

union FragU { us4 h[2]; bf16x8 v; };

__device__ __forceinline__ void ins3(float& a, float& b, float& c, float v){
  // keep (a<=b<=c) = 3 smallest seen
  if (v < c){
    c = v;
    if (c < b){ float t=b; b=c; c=t;
      if (b < a){ t=a; a=b; b=t; }
    }
  }
}

// ---------------------------------------------------------------------------
// Fused: bf16 MFMA GEMM (dots) + on-the-fly column norms + per-row top3-min
// over this block's 128 m-cols (per 64-col wave chunk) + positive capture.
// Tile: 128x128, BK=32, 4 waves (2x2), double-buffered LDS, tr_b16 frag loads.
// LDS tile layout: 4x16-subtiled [k/4][m/16][4][16] bf16; tr_read per-lane
// addr = subtile_base + (l&15)*8 BYTES (8-byte chunks! m162 semantics), so
// lane l elem j = subtile[row j][col l&15]  ->  m = l&15, k = (l>>4)*8 + j.
// ---------------------------------------------------------------------------
__global__ __launch_bounds__(256)
void fused_gemm_top3(const float* __restrict__ sketch,
                     const float* __restrict__ refk,
                     const int*   __restrict__ anchor,
                     const int*   __restrict__ posidx,
                     float* __restrict__ wtop,   // [NTOT][NCHUNK][3]
                     float* __restrict__ wpos)   // [NTOT]
{
  __shared__ union {
    unsigned short stage[16384];  // A: [0,8192) (2 bufs x 4096), B: [8192,16384)
    struct { float nA[16][128]; float nB[16][128]; } nrm;
  } sh;
  __shared__ int   p_lds[128];
  __shared__ float nA2[128], nB2[128];

  const int t = threadIdx.x;
  // XCD swizzle (1024 % 8 == 0 -> bijective): group same-batch blocks per XCD
  const uint32_t bid = blockIdx.x;
  const uint32_t L = (bid & 7u)*128u + (bid >> 3);
  const int b  = L >> 6;
  const int ni = (L >> 3) & 7;
  const int mi = L & 7;

  const float* Sb = sketch + (size_t)b*CDIM*HW;
  const float* Rb = refk   + (size_t)b*CDIM*HW;

  if (t < 128){
    const int n_g = ni*128 + t;
    const int* ap = anchor + (size_t)(b*NA + n_g)*3;
    p_lds[t] = ap[2]*FWID + ap[1];
  }
  __syncthreads();
  const int p0 = p_lds[0];
  int okf = 1;
  if (t < 128) okf = (p_lds[t] == p0 + t);
  const int contig = __syncthreads_and(okf);

  // staging mapping: thread covers cols colg..colg+7 (fixed), rows rowg & rowg+16
  const int colg = (t & 15)*8;
  const int rowg = t >> 4;
  const int mbase = mi*128;

  const int l  = t & 63;
  const int w  = t >> 6;
  const int wr = w >> 1, wc = w & 1;
  const uint32_t sh_base = (uint32_t)(uintptr_t)&sh.stage[0];
  // per-lane tr_read base: k-group (l>>4) -> +2048B (8 subtiles = k+8? no: 16
  // subtiles per k-group of 8 -> (l>>4)*16 subtiles * 128B = 2048B), wave
  // m-offset wr*64 (4 subtiles = 512B), lane chunk (l&15)*8 BYTES.
  const uint32_t laneA = ((uint32_t)(l>>4))*2048u + (uint32_t)wr*512u + (uint32_t)(l&15)*8u;
  const uint32_t laneB = ((uint32_t)(l>>4))*2048u + (uint32_t)wc*512u + (uint32_t)(l&15)*8u;

  // LDS store offset (ushort units), 4x16-subtiled: ((k>>2)*8 + (col>>4))*64 + (k&3)*16 + (col&15)
  const int off0 = ((rowg>>2)*8 + (colg>>4))*64 + (rowg&3)*16 + (colg&15);

  f32x4 acc[4][4];
  #pragma unroll
  for (int i=0;i<4;i++){
    #pragma unroll
    for (int j=0;j<4;j++){ f32x4 z = {0.f,0.f,0.f,0.f}; acc[i][j] = z; }
  }

  float sqA[8] = {0,0,0,0,0,0,0,0};
  float sqB[8] = {0,0,0,0,0,0,0,0};
  f4 ra[4], rb[4];

  auto load_tile = [&](int kt){
    const int c0 = kt*32 + rowg;
    const float* SA = Sb + (size_t)c0*HW;
    const float* RB = Rb + (size_t)c0*HW + mbase + colg;
    if (contig){
      const float* pA = SA + p0 + colg;
      ra[0] = *(const f4*)(pA);
      ra[1] = *(const f4*)(pA + 4);
      ra[2] = *(const f4*)(pA + 16*HW);
      ra[3] = *(const f4*)(pA + 16*HW + 4);
    } else {
      float* raf = (float*)ra;
      #pragma unroll
      for (int i=0;i<8;i++){
        const int pc = p_lds[colg + i];
        raf[i]   = SA[pc];
        raf[8+i] = SA[16*HW + pc];
      }
    }
    rb[0] = *(const f4*)(RB);
    rb[1] = *(const f4*)(RB + 4);
    rb[2] = *(const f4*)(RB + 16*HW);
    rb[3] = *(const f4*)(RB + 16*HW + 4);
  };

  auto cvt_store = [&](int buf){
    const float* raf = (const float*)ra;
    const float* rbf = (const float*)rb;
    us8 pk;
    #pragma unroll
    for (int i=0;i<8;i++){
      __hip_bfloat16 h = __float2bfloat16(raf[i]);
      pk[i] = __builtin_bit_cast(unsigned short, h);
      const float g = __bfloat162float(h);
      sqA[i] = fmaf(g, g, sqA[i]);
    }
    *(us8*)&sh.stage[buf*4096 + off0] = pk;
    #pragma unroll
    for (int i=0;i<8;i++){
      __hip_bfloat16 h = __float2bfloat16(raf[8+i]);
      pk[i] = __builtin_bit_cast(unsigned short, h);
      const float g = __bfloat162float(h);
      sqA[i] = fmaf(g, g, sqA[i]);
    }
    *(us8*)&sh.stage[buf*4096 + off0 + 2048] = pk;
    #pragma unroll
    for (int i=0;i<8;i++){
      __hip_bfloat16 h = __float2bfloat16(rbf[i]);
      pk[i] = __builtin_bit_cast(unsigned short, h);
      const float g = __bfloat162float(h);
      sqB[i] = fmaf(g, g, sqB[i]);
    }
    *(us8*)&sh.stage[8192 + buf*4096 + off0] = pk;
    #pragma unroll
    for (int i=0;i<8;i++){
      __hip_bfloat16 h = __float2bfloat16(rbf[8+i]);
      pk[i] = __builtin_bit_cast(unsigned short, h);
      const float g = __bfloat162float(h);
      sqB[i] = fmaf(g, g, sqB[i]);
    }
    *(us8*)&sh.stage[8192 + buf*4096 + off0 + 2048] = pk;
  };

  auto compute = [&](int buf){
    const uint32_t aaddr = sh_base + (uint32_t)buf*8192u + laneA;
    const uint32_t baddr = sh_base + 16384u + (uint32_t)buf*8192u + laneB;
    FragU A0,A1,A2,A3,B0,B1,B2,B3;
    A0.h[0]=tr_read<0>(aaddr);    A0.h[1]=tr_read<1024>(aaddr);
    A1.h[0]=tr_read<128>(aaddr);  A1.h[1]=tr_read<1152>(aaddr);
    A2.h[0]=tr_read<256>(aaddr);  A2.h[1]=tr_read<1280>(aaddr);
    A3.h[0]=tr_read<384>(aaddr);  A3.h[1]=tr_read<1408>(aaddr);
    B0.h[0]=tr_read<0>(baddr);    B0.h[1]=tr_read<1024>(baddr);
    B1.h[0]=tr_read<128>(baddr);  B1.h[1]=tr_read<1152>(baddr);
    B2.h[0]=tr_read<256>(baddr);  B2.h[1]=tr_read<1280>(baddr);
    B3.h[0]=tr_read<384>(baddr);  B3.h[1]=tr_read<1408>(baddr);
    asm volatile("s_waitcnt lgkmcnt(0)" ::: "memory");
    __builtin_amdgcn_sched_barrier(0);
    acc[0][0]=__builtin_amdgcn_mfma_f32_16x16x32_bf16(A0.v,B0.v,acc[0][0],0,0,0);
    acc[0][1]=__builtin_amdgcn_mfma_f32_16x16x32_bf16(A0.v,B1.v,acc[0][1],0,0,0);
    acc[0][2]=__builtin_amdgcn_mfma_f32_16x16x32_bf16(A0.v,B2.v,acc[0][2],0,0,0);
    acc[0][3]=__builtin_amdgcn_mfma_f32_16x16x32_bf16(A0.v,B3.v,acc[0][3],0,0,0);
    acc[1][0]=__builtin_amdgcn_mfma_f32_16x16x32_bf16(A1.v,B0.v,acc[1][0],0,0,0);
    acc[1][1]=__builtin_amdgcn_mfma_f32_16x16x32_bf16(A1.v,B1.v,acc[1][1],0,0,0);
    acc[1][2]=__builtin_amdgcn_mfma_f32_16x16x32_bf16(A1.v,B2.v,acc[1][2],0,0,0);
    acc[1][3]=__builtin_amdgcn_mfma_f32_16x16x32_bf16(A1.v,B3.v,acc[1][3],0,0,0);
    acc[2][0]=__builtin_amdgcn_mfma_f32_16x16x32_bf16(A2.v,B0.v,acc[2][0],0,0,0);
    acc[2][1]=__builtin_amdgcn_mfma_f32_16x16x32_bf16(A2.v,B1.v,acc[2][1],0,0,0);
    acc[2][2]=__builtin_amdgcn_mfma_f32_16x16x32_bf16(A2.v,B2.v,acc[2][2],0,0,0);
    acc[2][3]=__builtin_amdgcn_mfma_f32_16x16x32_bf16(A2.v,B3.v,acc[2][3],0,0,0);
    acc[3][0]=__builtin_amdgcn_mfma_f32_16x16x32_bf16(A3.v,B0.v,acc[3][0],0,0,0);
    acc[3][1]=__builtin_amdgcn_mfma_f32_16x16x32_bf16(A3.v,B1.v,acc[3][1],0,0,0);
    acc[3][2]=__builtin_amdgcn_mfma_f32_16x16x32_bf16(A3.v,B2.v,acc[3][2],0,0,0);
    acc[3][3]=__builtin_amdgcn_mfma_f32_16x16x32_bf16(A3.v,B3.v,acc[3][3],0,0,0);
  };

  // ---- main K loop: 32 tiles of BK=32, double-buffered ----
  load_tile(0);
  cvt_store(0);
  __syncthreads();
  int buf = 0;
  for (int kt = 0; kt < 32; ++kt){
    if (kt < 31) load_tile(kt+1);
    compute(buf);
    if (kt < 31) cvt_store(buf^1);
    __syncthreads();
    buf ^= 1;
  }

  // ---- norm reduction (reuse staging LDS) ----
  #pragma unroll
  for (int i=0;i<8;i++) sh.nrm.nA[rowg][colg+i] = sqA[i];
  #pragma unroll
  for (int i=0;i<8;i++) sh.nrm.nB[rowg][colg+i] = sqB[i];
  __syncthreads();
  if (t < 128){
    float s = 0.f;
    #pragma unroll
    for (int r=0;r<16;r++) s += sh.nrm.nA[r][t];
    nA2[t] = s;
  } else {
    const int c2 = t - 128;
    float s = 0.f;
    #pragma unroll
    for (int r=0;r<16;r++) s += sh.nrm.nB[r][c2];
    nB2[c2] = s;
  }
  __syncthreads();

  // ---- epilogue: normalize, positive capture, per-row top3-min ----
  float rncol[4];
  #pragma unroll
  for (int nf=0;nf<4;nf++) rncol[nf] = sqrtf(nB2[wc*64 + nf*16 + (l&15)]);

  #pragma unroll
  for (int mf=0; mf<4; ++mf){
    #pragma unroll
    for (int r=0; r<4; ++r){
      const int row_l = wr*64 + mf*16 + (l>>4)*4 + r;   // D: col=lane&15, row=(lane>>4)*4+reg
      const int n_g   = ni*128 + row_l;
      const float an  = sqrtf(nA2[row_l]);
      const float v0 = acc[mf][0][r] / fmaxf(an*rncol[0], 1e-8f);
      const float v1 = acc[mf][1][r] / fmaxf(an*rncol[1], 1e-8f);
      const float v2 = acc[mf][2][r] / fmaxf(an*rncol[2], 1e-8f);
      const float v3 = acc[mf][3][r] / fmaxf(an*rncol[3], 1e-8f);

      const int* pp = posidx + (size_t)(b*NA + n_g)*3;
      const int q  = pp[2]*FWID + pp[1];
      const int ql = q - (mbase + wc*64);
      if (ql >= 0 && ql < 64 && (ql & 15) == (l & 15)){
        const int sel = ql >> 4;
        const float pv = sel==0 ? v0 : sel==1 ? v1 : sel==2 ? v2 : v3;
        wpos[b*NA + n_g] = pv;
      }

      float x=1e30f, y=1e30f, z=1e30f;
      ins3(x,y,z,v0); ins3(x,y,z,v1); ins3(x,y,z,v2); ins3(x,y,z,v3);
      #pragma unroll
      for (int m=1; m<16; m<<=1){
        const float ox = __shfl_xor(x, m);
        const float oy = __shfl_xor(y, m);
        const float oz = __shfl_xor(z, m);
        ins3(x,y,z,ox); ins3(x,y,z,oy); ins3(x,y,z,oz);
      }
      if ((l & 15) == 0){
        float* dst = wtop + ((size_t)(b*NA + n_g)*NCHUNK + (mi*2 + wc))*3;
        dst[0]=x; dst[1]=y; dst[2]=z;
      }
    }
  }
}

// ---------------------------------------------------------------------------
__global__ __launch_bounds__(256)
void merge_top3(const float* __restrict__ wtop, const float* __restrict__ wpos,
                float* __restrict__ partial){
  __shared__ float red[256];
  const int id = blockIdx.x*256 + threadIdx.x;   // 0..16383
  const float* src = wtop + (size_t)id*(NCHUNK*3);
  float x=1e30f, y=1e30f, z=1e30f;
  #pragma unroll
  for (int i=0;i<NCHUNK*3;i++) ins3(x,y,z, src[i]);
  const float loss = fmaxf((x+y+z) - wpos[id] + MARGIN, 0.0f);
  red[threadIdx.x] = loss;
  __syncthreads();
  for (int s=128; s>0; s>>=1){
    if (threadIdx.x < s) red[threadIdx.x] += red[threadIdx.x+s];
    __syncthreads();
  }
  if (threadIdx.x == 0) partial[blockIdx.x] = red[0];
}

__global__ void final_sum(const float* __restrict__ partial, float* __restrict__ out){
  float v = partial[threadIdx.x];  // 64 threads = 1 wave
  #pragma unroll
  for (int off=32; off>0; off>>=1) v += __shfl_down(v, off);
  if (threadIdx.x == 0) out[0] = v / (1e-6f + (float)NTOT);
}

// ---------------------------------------------------------------------------
extern "C" void kernel_launch(void* const* d_in, const int* in_sizes, int n_in,
                              void* d_out, int out_size, void* d_ws, size_t ws_size,
                              hipStream_t stream){
  const float* sketch = (const float*)d_in[0];
  const float* refk   = (const float*)d_in[1];
  const int*   anchor = (const int*)d_in[2];
  const int*   posidx = (const int*)d_in[3];
  float* out = (float*)d_out;

  float* wtop    = (float*)d_ws;                       // NTOT*NCHUNK*3 floats
  float* wpos    = wtop + (size_t)NTOT*NCHUNK*3;       // NTOT floats
  float* partial = wpos + NTOT;                        // 64 floats

  fused_gemm_top3<<<dim3(1024), dim3(256), 0, stream>>>(sketch, refk, anchor, posidx, wtop, wpos);
  merge_top3<<<dim3(64), dim3(256), 0, stream>>>(wtop, wpos, partial);
  final_sum<<<dim3(1), dim3(64), 0, stream>>>(partial, out);
}

// Round 3
// 134.035 us; speedup vs baseline: 1.1075x; 1.1075x over previous
//
#include <hip/hip_runtime.h>
#include <hip/hip_bf16.h>
#include <stdint.h>

// ---------------- problem constants ----------------
#define BATCH 16
#define CDIM  1024
#define FWID  32
#define HW    1024
#define NA    1024
#define NTOT  (BATCH*NA)    // 16384
#define NCHUNK 16           // 8 m-blocks * 2 waves in N
#define MARGIN 0.6f

typedef __bf16 bf16x8 __attribute__((ext_vector_type(8)));
typedef float  f32x4  __attribute__((ext_vector_type(4)));
typedef unsigned short us4 __attribute__((ext_vector_type(4)));
typedef unsigned short us8 __attribute__((ext_vector_type(8)));
typedef float  f4     __attribute__((ext_vector_type(4)));

template<int OFF>
__device__ __forceinline__ us4 tr_read(uint32_t addr){
  us4 r;
  asm volatile("ds_read_b64_tr_b16 %0, %1 offset:%2" : "=v"(r) : "v"(addr), "n"(OFF));
  return r;
}

__device__ __forceinline__ void gload16(const unsigned short* g, unsigned short* l){
  __builtin_amdgcn_global_load_lds((const __attribute__((address_space(1))) void*)g,
                                   (__attribute__((address_space(3))) void*)l, 16, 0, 0);
}

union FragU { us4 h[2]; bf16x8 v; };

__device__ __forceinline__ void ins3(float& a, float& b, float& c, float v){
  if (v < c){
    c = v;
    if (c < b){ float t=b; b=c; c=t;
      if (b < a){ t=a; a=b; b=t; }
    }
  }
}

// ---------------------------------------------------------------------------
// Pass 1: fp32 -> bf16 (same [C][HW] layout) + partial square-sums per (b,hw).
// grid: [e(2)][b(16)][q(32)] = 1024 blocks, 256 threads; block converts 32 c-rows.
// ---------------------------------------------------------------------------
__global__ __launch_bounds__(256)
void convert_norm(const float* __restrict__ S, const float* __restrict__ R,
                  unsigned short* __restrict__ bfS, unsigned short* __restrict__ bfR,
                  float* __restrict__ pnorm){
  const int blk = blockIdx.x;
  const int e  = blk >> 9;
  const int bq = blk & 511;
  const size_t base = (size_t)bq * 32768;   // (b*32+q) * 32rows * 1024
  const float* src = (e ? R : S) + base;
  unsigned short* dst = (e ? bfR : bfS) + base;
  const int hw0 = threadIdx.x * 4;
  float s0=0.f, s1=0.f, s2=0.f, s3=0.f;
  #pragma unroll 4
  for (int ci=0; ci<32; ++ci){
    const f4 v = *(const f4*)(src + (size_t)ci*HW + hw0);
    us4 pk;
    __hip_bfloat16 h0 = __float2bfloat16(v[0]);
    __hip_bfloat16 h1 = __float2bfloat16(v[1]);
    __hip_bfloat16 h2 = __float2bfloat16(v[2]);
    __hip_bfloat16 h3 = __float2bfloat16(v[3]);
    pk[0] = __builtin_bit_cast(unsigned short, h0);
    pk[1] = __builtin_bit_cast(unsigned short, h1);
    pk[2] = __builtin_bit_cast(unsigned short, h2);
    pk[3] = __builtin_bit_cast(unsigned short, h3);
    const float g0 = __bfloat162float(h0), g1 = __bfloat162float(h1);
    const float g2 = __bfloat162float(h2), g3 = __bfloat162float(h3);
    s0 = fmaf(g0,g0,s0); s1 = fmaf(g1,g1,s1);
    s2 = fmaf(g2,g2,s2); s3 = fmaf(g3,g3,s3);
    *(us4*)(dst + (size_t)ci*HW + hw0) = pk;
  }
  f4 o = {s0,s1,s2,s3};
  *(f4*)(pnorm + (size_t)blk*HW + hw0) = o;
}

// grid: 32 blocks [e*16+b], 256 threads; snorm = sqrt(sum of partials)
__global__ __launch_bounds__(256)
void norm_reduce(const float* __restrict__ pnorm, float* __restrict__ snorm){
  const int eb = blockIdx.x;       // e*16 + b
  const int hw0 = threadIdx.x * 4;
  f4 a = {0.f,0.f,0.f,0.f};
  #pragma unroll
  for (int q=0; q<32; ++q){
    const f4 p = *(const f4*)(pnorm + ((size_t)eb*32 + q)*HW + hw0);
    a[0]+=p[0]; a[1]+=p[1]; a[2]+=p[2]; a[3]+=p[3];
  }
  f4 o = {sqrtf(a[0]), sqrtf(a[1]), sqrtf(a[2]), sqrtf(a[3])};
  *(f4*)(snorm + (size_t)eb*HW + hw0) = o;
}

// ---------------------------------------------------------------------------
// Pass 2: bf16 MFMA GEMM staged via global_load_lds (pre-swizzled per-lane src
// -> same subtiled LDS layout as the verified v1), tr_b16 frag loads, epilogue
// with precomputed norms + per-row top3-min + positive capture.
// ---------------------------------------------------------------------------
__global__ __launch_bounds__(256)
void fused_gemm_top3_v2(const unsigned short* __restrict__ bfS,
                        const unsigned short* __restrict__ bfR,
                        const float* __restrict__ snorm,
                        const int*   __restrict__ anchor,
                        const int*   __restrict__ posidx,
                        float* __restrict__ wtop,   // [NTOT][NCHUNK][3]
                        float* __restrict__ wpos)   // [NTOT]
{
  __shared__ unsigned short stage[16384]; // A: [0,8192) us (2 bufs x 4096), B: [8192,16384)
  __shared__ int   p_lds[128];
  __shared__ float nAs[128], nBs[128];

  const int t = threadIdx.x;
  const uint32_t bid = blockIdx.x;
  const uint32_t L = (bid & 7u)*128u + (bid >> 3);   // XCD swizzle (bijective: 1024%8==0)
  const int b  = L >> 6;
  const int ni = (L >> 3) & 7;
  const int mi = L & 7;

  const unsigned short* Sb = bfS + (size_t)b*CDIM*HW;
  const unsigned short* Rb = bfR + (size_t)b*CDIM*HW;

  if (t < 128){
    const int n_g = ni*128 + t;
    const int* ap = anchor + (size_t)(b*NA + n_g)*3;
    p_lds[t] = ap[2]*FWID + ap[1];
  }
  __syncthreads();
  const int p0 = p_lds[0];
  int okf = 1;
  if (t < 128) okf = (p_lds[t] == p0 + t);
  const int contig = __syncthreads_and(okf);
  const int fastA = contig && ((p0 & 7) == 0);

  const int mbase = mi*128;
  const int l  = t & 63;
  const int w  = t >> 6;
  const int wr = w >> 1, wc = w & 1;
  const uint32_t sh_base = (uint32_t)(uintptr_t)&stage[0];
  const uint32_t laneA = ((uint32_t)(l>>4))*2048u + (uint32_t)wr*512u + (uint32_t)(l&15)*8u;
  const uint32_t laneB = ((uint32_t)(l>>4))*2048u + (uint32_t)wc*512u + (uint32_t)(l&15)*8u;

  // staging chunk coords for inst i in {0,1}: k=(2w+i)*4+((l&7)>>1), m=(l>>3)*16+(l&1)*8
  const int kk0 = (w*2+0)*4 + ((l&7)>>1);
  const int kk1 = (w*2+1)*4 + ((l&7)>>1);
  const int mm  = (l>>3)*16 + (l&1)*8;
  const size_t oe0 = (size_t)kk0*HW + mm;   // element offset within 32x(...) tile
  const size_t oe1 = (size_t)kk1*HW + mm;
  const unsigned short* Abase = Sb + p0;      // valid when fastA
  const unsigned short* Bbase = Rb + mbase;

  f32x4 acc[4][4];
  #pragma unroll
  for (int i=0;i<4;i++){
    #pragma unroll
    for (int j=0;j<4;j++){ f32x4 z = {0.f,0.f,0.f,0.f}; acc[i][j] = z; }
  }

  auto stage_fn = [&](int buf, int kt){
    const size_t koff = (size_t)kt * 32768;   // 32 rows * 1024
    unsigned short* lA = &stage[buf*4096 + w*1024];
    unsigned short* lB = &stage[8192 + buf*4096 + w*1024];
    if (fastA){
      gload16(Abase + koff + oe0, lA);
      gload16(Abase + koff + oe1, lA + 512);
    } else {
      // reg-staged gather fallback (same layout)
      us8 pk0, pk1;
      #pragma unroll
      for (int j=0;j<8;j++) pk0[j] = Sb[koff + (size_t)kk0*HW + p_lds[mm + j]];
      #pragma unroll
      for (int j=0;j<8;j++) pk1[j] = Sb[koff + (size_t)kk1*HW + p_lds[mm + j]];
      *(us8*)&stage[buf*4096 + w*1024 + l*8]       = pk0;
      *(us8*)&stage[buf*4096 + w*1024 + 512 + l*8] = pk1;
    }
    gload16(Bbase + koff + oe0, lB);
    gload16(Bbase + koff + oe1, lB + 512);
  };

  auto compute = [&](int buf){
    const uint32_t aaddr = sh_base + (uint32_t)buf*8192u + laneA;
    const uint32_t baddr = sh_base + 16384u + (uint32_t)buf*8192u + laneB;
    FragU A0,A1,A2,A3,B0,B1,B2,B3;
    A0.h[0]=tr_read<0>(aaddr);    A0.h[1]=tr_read<1024>(aaddr);
    A1.h[0]=tr_read<128>(aaddr);  A1.h[1]=tr_read<1152>(aaddr);
    A2.h[0]=tr_read<256>(aaddr);  A2.h[1]=tr_read<1280>(aaddr);
    A3.h[0]=tr_read<384>(aaddr);  A3.h[1]=tr_read<1408>(aaddr);
    B0.h[0]=tr_read<0>(baddr);    B0.h[1]=tr_read<1024>(baddr);
    B1.h[0]=tr_read<128>(baddr);  B1.h[1]=tr_read<1152>(baddr);
    B2.h[0]=tr_read<256>(baddr);  B2.h[1]=tr_read<1280>(baddr);
    B3.h[0]=tr_read<384>(baddr);  B3.h[1]=tr_read<1408>(baddr);
    asm volatile("s_waitcnt lgkmcnt(0)" ::: "memory");
    __builtin_amdgcn_sched_barrier(0);
    acc[0][0]=__builtin_amdgcn_mfma_f32_16x16x32_bf16(A0.v,B0.v,acc[0][0],0,0,0);
    acc[0][1]=__builtin_amdgcn_mfma_f32_16x16x32_bf16(A0.v,B1.v,acc[0][1],0,0,0);
    acc[0][2]=__builtin_amdgcn_mfma_f32_16x16x32_bf16(A0.v,B2.v,acc[0][2],0,0,0);
    acc[0][3]=__builtin_amdgcn_mfma_f32_16x16x32_bf16(A0.v,B3.v,acc[0][3],0,0,0);
    acc[1][0]=__builtin_amdgcn_mfma_f32_16x16x32_bf16(A1.v,B0.v,acc[1][0],0,0,0);
    acc[1][1]=__builtin_amdgcn_mfma_f32_16x16x32_bf16(A1.v,B1.v,acc[1][1],0,0,0);
    acc[1][2]=__builtin_amdgcn_mfma_f32_16x16x32_bf16(A1.v,B2.v,acc[1][2],0,0,0);
    acc[1][3]=__builtin_amdgcn_mfma_f32_16x16x32_bf16(A1.v,B3.v,acc[1][3],0,0,0);
    acc[2][0]=__builtin_amdgcn_mfma_f32_16x16x32_bf16(A2.v,B0.v,acc[2][0],0,0,0);
    acc[2][1]=__builtin_amdgcn_mfma_f32_16x16x32_bf16(A2.v,B1.v,acc[2][1],0,0,0);
    acc[2][2]=__builtin_amdgcn_mfma_f32_16x16x32_bf16(A2.v,B2.v,acc[2][2],0,0,0);
    acc[2][3]=__builtin_amdgcn_mfma_f32_16x16x32_bf16(A2.v,B3.v,acc[2][3],0,0,0);
    acc[3][0]=__builtin_amdgcn_mfma_f32_16x16x32_bf16(A3.v,B0.v,acc[3][0],0,0,0);
    acc[3][1]=__builtin_amdgcn_mfma_f32_16x16x32_bf16(A3.v,B1.v,acc[3][1],0,0,0);
    acc[3][2]=__builtin_amdgcn_mfma_f32_16x16x32_bf16(A3.v,B2.v,acc[3][2],0,0,0);
    acc[3][3]=__builtin_amdgcn_mfma_f32_16x16x32_bf16(A3.v,B3.v,acc[3][3],0,0,0);
  };

  // ---- main K loop: 32 tiles of BK=32, double-buffered, issue-early staging ----
  stage_fn(0, 0);
  __syncthreads();
  int buf = 0;
  for (int kt = 0; kt < 32; ++kt){
    if (kt < 31) stage_fn(buf^1, kt+1);
    compute(buf);
    __syncthreads();   // drains vmcnt (staging) + ensures frag reads done
    buf ^= 1;
  }

  // ---- norms from precomputed snorm ----
  if (t < 128) nAs[t] = snorm[(size_t)b*HW + p_lds[t]];
  else         nBs[t-128] = snorm[(size_t)(BATCH + b)*HW + mbase + (t-128)];
  __syncthreads();

  // ---- epilogue: normalize, positive capture, per-row top3-min ----
  float rncol[4];
  #pragma unroll
  for (int nf=0;nf<4;nf++) rncol[nf] = nBs[wc*64 + nf*16 + (l&15)];

  #pragma unroll
  for (int mf=0; mf<4; ++mf){
    #pragma unroll
    for (int r=0; r<4; ++r){
      const int row_l = wr*64 + mf*16 + (l>>4)*4 + r;   // D: col=lane&15, row=(lane>>4)*4+reg
      const int n_g   = ni*128 + row_l;
      const float an  = nAs[row_l];
      const float v0 = acc[mf][0][r] / fmaxf(an*rncol[0], 1e-8f);
      const float v1 = acc[mf][1][r] / fmaxf(an*rncol[1], 1e-8f);
      const float v2 = acc[mf][2][r] / fmaxf(an*rncol[2], 1e-8f);
      const float v3 = acc[mf][3][r] / fmaxf(an*rncol[3], 1e-8f);

      const int* pp = posidx + (size_t)(b*NA + n_g)*3;
      const int q  = pp[2]*FWID + pp[1];
      const int ql = q - (mbase + wc*64);
      if (ql >= 0 && ql < 64 && (ql & 15) == (l & 15)){
        const int sel = ql >> 4;
        const float pv = sel==0 ? v0 : sel==1 ? v1 : sel==2 ? v2 : v3;
        wpos[b*NA + n_g] = pv;
      }

      float x=1e30f, y=1e30f, z=1e30f;
      ins3(x,y,z,v0); ins3(x,y,z,v1); ins3(x,y,z,v2); ins3(x,y,z,v3);
      #pragma unroll
      for (int m=1; m<16; m<<=1){
        const float ox = __shfl_xor(x, m);
        const float oy = __shfl_xor(y, m);
        const float oz = __shfl_xor(z, m);
        ins3(x,y,z,ox); ins3(x,y,z,oy); ins3(x,y,z,oz);
      }
      if ((l & 15) == 0){
        float* dst = wtop + ((size_t)(b*NA + n_g)*NCHUNK + (mi*2 + wc))*3;
        dst[0]=x; dst[1]=y; dst[2]=z;
      }
    }
  }
}

// ---------------------------------------------------------------------------
// v1 (verified) fused kernel — fallback when workspace is too small.
// ---------------------------------------------------------------------------
__global__ __launch_bounds__(256)
void fused_gemm_top3_v1(const float* __restrict__ sketch,
                        const float* __restrict__ refk,
                        const int*   __restrict__ anchor,
                        const int*   __restrict__ posidx,
                        float* __restrict__ wtop,
                        float* __restrict__ wpos)
{
  __shared__ union {
    unsigned short stage[16384];
    struct { float nA[16][128]; float nB[16][128]; } nrm;
  } sh;
  __shared__ int   p_lds[128];
  __shared__ float nA2[128], nB2[128];

  const int t = threadIdx.x;
  const uint32_t bid = blockIdx.x;
  const uint32_t L = (bid & 7u)*128u + (bid >> 3);
  const int b  = L >> 6;
  const int ni = (L >> 3) & 7;
  const int mi = L & 7;

  const float* Sb = sketch + (size_t)b*CDIM*HW;
  const float* Rb = refk   + (size_t)b*CDIM*HW;

  if (t < 128){
    const int n_g = ni*128 + t;
    const int* ap = anchor + (size_t)(b*NA + n_g)*3;
    p_lds[t] = ap[2]*FWID + ap[1];
  }
  __syncthreads();
  const int p0 = p_lds[0];
  int okf = 1;
  if (t < 128) okf = (p_lds[t] == p0 + t);
  const int contig = __syncthreads_and(okf);

  const int colg = (t & 15)*8;
  const int rowg = t >> 4;
  const int mbase = mi*128;

  const int l  = t & 63;
  const int w  = t >> 6;
  const int wr = w >> 1, wc = w & 1;
  const uint32_t sh_base = (uint32_t)(uintptr_t)&sh.stage[0];
  const uint32_t laneA = ((uint32_t)(l>>4))*2048u + (uint32_t)wr*512u + (uint32_t)(l&15)*8u;
  const uint32_t laneB = ((uint32_t)(l>>4))*2048u + (uint32_t)wc*512u + (uint32_t)(l&15)*8u;
  const int off0 = ((rowg>>2)*8 + (colg>>4))*64 + (rowg&3)*16 + (colg&15);

  f32x4 acc[4][4];
  #pragma unroll
  for (int i=0;i<4;i++){
    #pragma unroll
    for (int j=0;j<4;j++){ f32x4 z = {0.f,0.f,0.f,0.f}; acc[i][j] = z; }
  }

  float sqA[8] = {0,0,0,0,0,0,0,0};
  float sqB[8] = {0,0,0,0,0,0,0,0};
  f4 ra[4], rb[4];

  auto load_tile = [&](int kt){
    const int c0 = kt*32 + rowg;
    const float* SA = Sb + (size_t)c0*HW;
    const float* RB = Rb + (size_t)c0*HW + mbase + colg;
    if (contig){
      const float* pA = SA + p0 + colg;
      ra[0] = *(const f4*)(pA);
      ra[1] = *(const f4*)(pA + 4);
      ra[2] = *(const f4*)(pA + 16*HW);
      ra[3] = *(const f4*)(pA + 16*HW + 4);
    } else {
      float* raf = (float*)ra;
      #pragma unroll
      for (int i=0;i<8;i++){
        const int pc = p_lds[colg + i];
        raf[i]   = SA[pc];
        raf[8+i] = SA[16*HW + pc];
      }
    }
    rb[0] = *(const f4*)(RB);
    rb[1] = *(const f4*)(RB + 4);
    rb[2] = *(const f4*)(RB + 16*HW);
    rb[3] = *(const f4*)(RB + 16*HW + 4);
  };

  auto cvt_store = [&](int buf){
    const float* raf = (const float*)ra;
    const float* rbf = (const float*)rb;
    us8 pk;
    #pragma unroll
    for (int i=0;i<8;i++){
      __hip_bfloat16 h = __float2bfloat16(raf[i]);
      pk[i] = __builtin_bit_cast(unsigned short, h);
      const float g = __bfloat162float(h);
      sqA[i] = fmaf(g, g, sqA[i]);
    }
    *(us8*)&sh.stage[buf*4096 + off0] = pk;
    #pragma unroll
    for (int i=0;i<8;i++){
      __hip_bfloat16 h = __float2bfloat16(raf[8+i]);
      pk[i] = __builtin_bit_cast(unsigned short, h);
      const float g = __bfloat162float(h);
      sqA[i] = fmaf(g, g, sqA[i]);
    }
    *(us8*)&sh.stage[buf*4096 + off0 + 2048] = pk;
    #pragma unroll
    for (int i=0;i<8;i++){
      __hip_bfloat16 h = __float2bfloat16(rbf[i]);
      pk[i] = __builtin_bit_cast(unsigned short, h);
      const float g = __bfloat162float(h);
      sqB[i] = fmaf(g, g, sqB[i]);
    }
    *(us8*)&sh.stage[8192 + buf*4096 + off0] = pk;
    #pragma unroll
    for (int i=0;i<8;i++){
      __hip_bfloat16 h = __float2bfloat16(rbf[8+i]);
      pk[i] = __builtin_bit_cast(unsigned short, h);
      const float g = __bfloat162float(h);
      sqB[i] = fmaf(g, g, sqB[i]);
    }
    *(us8*)&sh.stage[8192 + buf*4096 + off0 + 2048] = pk;
  };

  auto compute = [&](int buf){
    const uint32_t aaddr = sh_base + (uint32_t)buf*8192u + laneA;
    const uint32_t baddr = sh_base + 16384u + (uint32_t)buf*8192u + laneB;
    FragU A0,A1,A2,A3,B0,B1,B2,B3;
    A0.h[0]=tr_read<0>(aaddr);    A0.h[1]=tr_read<1024>(aaddr);
    A1.h[0]=tr_read<128>(aaddr);  A1.h[1]=tr_read<1152>(aaddr);
    A2.h[0]=tr_read<256>(aaddr);  A2.h[1]=tr_read<1280>(aaddr);
    A3.h[0]=tr_read<384>(aaddr);  A3.h[1]=tr_read<1408>(aaddr);
    B0.h[0]=tr_read<0>(baddr);    B0.h[1]=tr_read<1024>(baddr);
    B1.h[0]=tr_read<128>(baddr);  B1.h[1]=tr_read<1152>(baddr);
    B2.h[0]=tr_read<256>(baddr);  B2.h[1]=tr_read<1280>(baddr);
    B3.h[0]=tr_read<384>(baddr);  B3.h[1]=tr_read<1408>(baddr);
    asm volatile("s_waitcnt lgkmcnt(0)" ::: "memory");
    __builtin_amdgcn_sched_barrier(0);
    acc[0][0]=__builtin_amdgcn_mfma_f32_16x16x32_bf16(A0.v,B0.v,acc[0][0],0,0,0);
    acc[0][1]=__builtin_amdgcn_mfma_f32_16x16x32_bf16(A0.v,B1.v,acc[0][1],0,0,0);
    acc[0][2]=__builtin_amdgcn_mfma_f32_16x16x32_bf16(A0.v,B2.v,acc[0][2],0,0,0);
    acc[0][3]=__builtin_amdgcn_mfma_f32_16x16x32_bf16(A0.v,B3.v,acc[0][3],0,0,0);
    acc[1][0]=__builtin_amdgcn_mfma_f32_16x16x32_bf16(A1.v,B0.v,acc[1][0],0,0,0);
    acc[1][1]=__builtin_amdgcn_mfma_f32_16x16x32_bf16(A1.v,B1.v,acc[1][1],0,0,0);
    acc[1][2]=__builtin_amdgcn_mfma_f32_16x16x32_bf16(A1.v,B2.v,acc[1][2],0,0,0);
    acc[1][3]=__builtin_amdgcn_mfma_f32_16x16x32_bf16(A1.v,B3.v,acc[1][3],0,0,0);
    acc[2][0]=__builtin_amdgcn_mfma_f32_16x16x32_bf16(A2.v,B0.v,acc[2][0],0,0,0);
    acc[2][1]=__builtin_amdgcn_mfma_f32_16x16x32_bf16(A2.v,B1.v,acc[2][1],0,0,0);
    acc[2][2]=__builtin_amdgcn_mfma_f32_16x16x32_bf16(A2.v,B2.v,acc[2][2],0,0,0);
    acc[2][3]=__builtin_amdgcn_mfma_f32_16x16x32_bf16(A2.v,B3.v,acc[2][3],0,0,0);
    acc[3][0]=__builtin_amdgcn_mfma_f32_16x16x32_bf16(A3.v,B0.v,acc[3][0],0,0,0);
    acc[3][1]=__builtin_amdgcn_mfma_f32_16x16x32_bf16(A3.v,B1.v,acc[3][1],0,0,0);
    acc[3][2]=__builtin_amdgcn_mfma_f32_16x16x32_bf16(A3.v,B2.v,acc[3][2],0,0,0);
    acc[3][3]=__builtin_amdgcn_mfma_f32_16x16x32_bf16(A3.v,B3.v,acc[3][3],0,0,0);
  };

  load_tile(0);
  cvt_store(0);
  __syncthreads();
  int buf = 0;
  for (int kt = 0; kt < 32; ++kt){
    if (kt < 31) load_tile(kt+1);
    compute(buf);
    if (kt < 31) cvt_store(buf^1);
    __syncthreads();
    buf ^= 1;
  }

  #pragma unroll
  for (int i=0;i<8;i++) sh.nrm.nA[rowg][colg+i] = sqA[i];
  #pragma unroll
  for (int i=0;i<8;i++) sh.nrm.nB[rowg][colg+i] = sqB[i];
  __syncthreads();
  if (t < 128){
    float s = 0.f;
    #pragma unroll
    for (int r=0;r<16;r++) s += sh.nrm.nA[r][t];
    nA2[t] = s;
  } else {
    const int c2 = t - 128;
    float s = 0.f;
    #pragma unroll
    for (int r=0;r<16;r++) s += sh.nrm.nB[r][c2];
    nB2[c2] = s;
  }
  __syncthreads();

  float rncol[4];
  #pragma unroll
  for (int nf=0;nf<4;nf++) rncol[nf] = sqrtf(nB2[wc*64 + nf*16 + (l&15)]);

  #pragma unroll
  for (int mf=0; mf<4; ++mf){
    #pragma unroll
    for (int r=0; r<4; ++r){
      const int row_l = wr*64 + mf*16 + (l>>4)*4 + r;
      const int n_g   = ni*128 + row_l;
      const float an  = sqrtf(nA2[row_l]);
      const float v0 = acc[mf][0][r] / fmaxf(an*rncol[0], 1e-8f);
      const float v1 = acc[mf][1][r] / fmaxf(an*rncol[1], 1e-8f);
      const float v2 = acc[mf][2][r] / fmaxf(an*rncol[2], 1e-8f);
      const float v3 = acc[mf][3][r] / fmaxf(an*rncol[3], 1e-8f);

      const int* pp = posidx + (size_t)(b*NA + n_g)*3;
      const int q  = pp[2]*FWID + pp[1];
      const int ql = q - (mbase + wc*64);
      if (ql >= 0 && ql < 64 && (ql & 15) == (l & 15)){
        const int sel = ql >> 4;
        const float pv = sel==0 ? v0 : sel==1 ? v1 : sel==2 ? v2 : v3;
        wpos[b*NA + n_g] = pv;
      }

      float x=1e30f, y=1e30f, z=1e30f;
      ins3(x,y,z,v0); ins3(x,y,z,v1); ins3(x,y,z,v2); ins3(x,y,z,v3);
      #pragma unroll
      for (int m=1; m<16; m<<=1){
        const float ox = __shfl_xor(x, m);
        const float oy = __shfl_xor(y, m);
        const float oz = __shfl_xor(z, m);
        ins3(x,y,z,ox); ins3(x,y,z,oy); ins3(x,y,z,oz);
      }
      if ((l & 15) == 0){
        float* dst = wtop + ((size_t)(b*NA + n_g)*NCHUNK + (mi*2 + wc))*3;
        dst[0]=x; dst[1]=y; dst[2]=z;
      }
    }
  }
}

// ---------------------------------------------------------------------------
__global__ __launch_bounds__(256)
void merge_top3(const float* __restrict__ wtop, const float* __restrict__ wpos,
                float* __restrict__ partial){
  __shared__ float red[256];
  const int id = blockIdx.x*256 + threadIdx.x;
  const float* src = wtop + (size_t)id*(NCHUNK*3);
  float x=1e30f, y=1e30f, z=1e30f;
  #pragma unroll
  for (int i=0;i<NCHUNK*3;i++) ins3(x,y,z, src[i]);
  const float loss = fmaxf((x+y+z) - wpos[id] + MARGIN, 0.0f);
  red[threadIdx.x] = loss;
  __syncthreads();
  for (int s=128; s>0; s>>=1){
    if (threadIdx.x < s) red[threadIdx.x] += red[threadIdx.x+s];
    __syncthreads();
  }
  if (threadIdx.x == 0) partial[blockIdx.x] = red[0];
}

__global__ void final_sum(const float* __restrict__ partial, float* __restrict__ out){
  float v = partial[threadIdx.x];
  #pragma unroll
  for (int off=32; off>0; off>>=1) v += __shfl_down(v, off);
  if (threadIdx.x == 0) out[0] = v / (1e-6f + (float)NTOT);
}

// ---------------------------------------------------------------------------
extern "C" void kernel_launch(void* const* d_in, const int* in_sizes, int n_in,
                              void* d_out, int out_size, void* d_ws, size_t ws_size,
                              hipStream_t stream){
  const float* sketch = (const float*)d_in[0];
  const float* refk   = (const float*)d_in[1];
  const int*   anchor = (const int*)d_in[2];
  const int*   posidx = (const int*)d_in[3];
  float* out = (float*)d_out;

  float* wtop    = (float*)d_ws;                       // NTOT*NCHUNK*3 floats
  float* wpos    = wtop + (size_t)NTOT*NCHUNK*3;       // NTOT floats
  float* partial = wpos + NTOT;                        // 64 floats (+pad)
  unsigned short* bfS = (unsigned short*)(partial + 256);
  unsigned short* bfR = bfS + (size_t)BATCH*CDIM*HW;
  float* pnorm = (float*)(bfR + (size_t)BATCH*CDIM*HW);   // 1024*1024 floats
  float* snorm = pnorm + (size_t)1024*1024;               // 32*1024 floats
  const size_t need = (size_t)((char*)(snorm + 32*1024) - (char*)d_ws);

  if (ws_size >= need){
    convert_norm<<<dim3(1024), dim3(256), 0, stream>>>(sketch, refk, bfS, bfR, pnorm);
    norm_reduce<<<dim3(32), dim3(256), 0, stream>>>(pnorm, snorm);
    fused_gemm_top3_v2<<<dim3(1024), dim3(256), 0, stream>>>(bfS, bfR, snorm, anchor, posidx, wtop, wpos);
  } else {
    fused_gemm_top3_v1<<<dim3(1024), dim3(256), 0, stream>>>(sketch, refk, anchor, posidx, wtop, wpos);
  }
  merge_top3<<<dim3(64), dim3(256), 0, stream>>>(wtop, wpos, partial);
  final_sum<<<dim3(1), dim3(64), 0, stream>>>(partial, out);
}

// Round 4
// 123.188 us; speedup vs baseline: 1.2051x; 1.0881x over previous
//
#include <hip/hip_runtime.h>
#include <hip/hip_bf16.h>
#include <stdint.h>

// ---------------- problem constants ----------------
#define BATCH 16
#define CDIM  1024
#define FWID  32
#define HW    1024
#define NA    1024
#define NTOT  (BATCH*NA)    // 16384
#define NCHUNK 16           // 8 m-blocks * 2 waves in N
#define MARGIN 0.6f

typedef __bf16 bf16x8 __attribute__((ext_vector_type(8)));
typedef float  f32x4  __attribute__((ext_vector_type(4)));
typedef unsigned short us4 __attribute__((ext_vector_type(4)));
typedef unsigned short us8 __attribute__((ext_vector_type(8)));
typedef float  f4     __attribute__((ext_vector_type(4)));

template<int OFF>
__device__ __forceinline__ us4 tr_read(uint32_t addr){
  us4 r;
  asm volatile("ds_read_b64_tr_b16 %0, %1 offset:%2" : "=v"(r) : "v"(addr), "n"(OFF));
  return r;
}

__device__ __forceinline__ void gload16(const unsigned short* g, unsigned short* l){
  __builtin_amdgcn_global_load_lds((const __attribute__((address_space(1))) void*)g,
                                   (__attribute__((address_space(3))) void*)l, 16, 0, 0);
}

union FragU { us4 h[2]; bf16x8 v; };

__device__ __forceinline__ void ins3(float& a, float& b, float& c, float v){
  if (v < c){
    c = v;
    if (c < b){ float t=b; b=c; c=t;
      if (b < a){ t=a; a=b; b=t; }
    }
  }
}

// ---------------------------------------------------------------------------
// Pass 1: fp32 -> bf16 (same [C][HW] layout) + partial square-sums per (b,hw).
// ---------------------------------------------------------------------------
__global__ __launch_bounds__(256)
void convert_norm(const float* __restrict__ S, const float* __restrict__ R,
                  unsigned short* __restrict__ bfS, unsigned short* __restrict__ bfR,
                  float* __restrict__ pnorm){
  const int blk = blockIdx.x;
  const int e  = blk >> 9;
  const int bq = blk & 511;
  const size_t base = (size_t)bq * 32768;   // (b*32+q) * 32rows * 1024
  const float* src = (e ? R : S) + base;
  unsigned short* dst = (e ? bfR : bfS) + base;
  const int hw0 = threadIdx.x * 4;
  float s0=0.f, s1=0.f, s2=0.f, s3=0.f;
  #pragma unroll 4
  for (int ci=0; ci<32; ++ci){
    const f4 v = *(const f4*)(src + (size_t)ci*HW + hw0);
    us4 pk;
    __hip_bfloat16 h0 = __float2bfloat16(v[0]);
    __hip_bfloat16 h1 = __float2bfloat16(v[1]);
    __hip_bfloat16 h2 = __float2bfloat16(v[2]);
    __hip_bfloat16 h3 = __float2bfloat16(v[3]);
    pk[0] = __builtin_bit_cast(unsigned short, h0);
    pk[1] = __builtin_bit_cast(unsigned short, h1);
    pk[2] = __builtin_bit_cast(unsigned short, h2);
    pk[3] = __builtin_bit_cast(unsigned short, h3);
    const float g0 = __bfloat162float(h0), g1 = __bfloat162float(h1);
    const float g2 = __bfloat162float(h2), g3 = __bfloat162float(h3);
    s0 = fmaf(g0,g0,s0); s1 = fmaf(g1,g1,s1);
    s2 = fmaf(g2,g2,s2); s3 = fmaf(g3,g3,s3);
    *(us4*)(dst + (size_t)ci*HW + hw0) = pk;
  }
  f4 o = {s0,s1,s2,s3};
  *(f4*)(pnorm + (size_t)blk*HW + hw0) = o;
}

// grid: 32 blocks [e*16+b], 256 threads; snorm = sqrt(sum of partials)
__global__ __launch_bounds__(256)
void norm_reduce(const float* __restrict__ pnorm, float* __restrict__ snorm){
  const int eb = blockIdx.x;       // e*16 + b
  const int hw0 = threadIdx.x * 4;
  f4 a = {0.f,0.f,0.f,0.f};
  #pragma unroll
  for (int q=0; q<32; ++q){
    const f4 p = *(const f4*)(pnorm + ((size_t)eb*32 + q)*HW + hw0);
    a[0]+=p[0]; a[1]+=p[1]; a[2]+=p[2]; a[3]+=p[3];
  }
  f4 o = {sqrtf(a[0]), sqrtf(a[1]), sqrtf(a[2]), sqrtf(a[3])};
  *(f4*)(snorm + (size_t)eb*HW + hw0) = o;
}

// ---------------------------------------------------------------------------
// Pass 2: bf16 MFMA GEMM staged via global_load_lds, tr_b16 frag loads,
// counted-vmcnt pipelined K-loop (T4: never drain vmcnt in the main loop).
// ---------------------------------------------------------------------------
__global__ __launch_bounds__(256)
void fused_gemm_top3_v2(const unsigned short* __restrict__ bfS,
                        const unsigned short* __restrict__ bfR,
                        const float* __restrict__ snorm,
                        const int*   __restrict__ anchor,
                        const int*   __restrict__ posidx,
                        float* __restrict__ wtop,   // [NTOT][NCHUNK][3]
                        float* __restrict__ wpos)   // [NTOT]
{
  __shared__ unsigned short stage[16384]; // A: [0,8192) us (2 bufs x 4096), B: [8192,16384)
  __shared__ int   p_lds[128];
  __shared__ float nAs[128], nBs[128];

  const int t = threadIdx.x;
  const uint32_t bid = blockIdx.x;
  const uint32_t L = (bid & 7u)*128u + (bid >> 3);   // XCD swizzle (bijective: 1024%8==0)
  const int b  = L >> 6;
  const int ni = (L >> 3) & 7;
  const int mi = L & 7;

  const unsigned short* Sb = bfS + (size_t)b*CDIM*HW;
  const unsigned short* Rb = bfR + (size_t)b*CDIM*HW;

  if (t < 128){
    const int n_g = ni*128 + t;
    const int* ap = anchor + (size_t)(b*NA + n_g)*3;
    p_lds[t] = ap[2]*FWID + ap[1];
  }
  __syncthreads();
  const int p0 = p_lds[0];
  int okf = 1;
  if (t < 128) okf = (p_lds[t] == p0 + t);
  const int contig = __syncthreads_and(okf);
  const int fastA = contig && ((p0 & 7) == 0);

  const int mbase = mi*128;
  const int l  = t & 63;
  const int w  = t >> 6;
  const int wr = w >> 1, wc = w & 1;
  const uint32_t sh_base = (uint32_t)(uintptr_t)&stage[0];
  const uint32_t laneA = ((uint32_t)(l>>4))*2048u + (uint32_t)wr*512u + (uint32_t)(l&15)*8u;
  const uint32_t laneB = ((uint32_t)(l>>4))*2048u + (uint32_t)wc*512u + (uint32_t)(l&15)*8u;

  // staging chunk coords for inst i in {0,1}: k=(2w+i)*4+((l&7)>>1), m=(l>>3)*16+(l&1)*8
  const int kk0 = (w*2+0)*4 + ((l&7)>>1);
  const int kk1 = (w*2+1)*4 + ((l&7)>>1);
  const int mm  = (l>>3)*16 + (l&1)*8;
  const size_t oe0 = (size_t)kk0*HW + mm;   // element offset within 32x(...) tile
  const size_t oe1 = (size_t)kk1*HW + mm;
  const unsigned short* Abase = Sb + p0;      // valid when fastA
  const unsigned short* Bbase = Rb + mbase;

  f32x4 acc[4][4];
  #pragma unroll
  for (int i=0;i<4;i++){
    #pragma unroll
    for (int j=0;j<4;j++){ f32x4 z = {0.f,0.f,0.f,0.f}; acc[i][j] = z; }
  }

  auto stage_fn = [&](int buf, int kt){
    const size_t koff = (size_t)kt * 32768;   // 32 rows * 1024
    unsigned short* lA = &stage[buf*4096 + w*1024];
    unsigned short* lB = &stage[8192 + buf*4096 + w*1024];
    if (fastA){
      gload16(Abase + koff + oe0, lA);
      gload16(Abase + koff + oe1, lA + 512);
    } else {
      // reg-staged gather fallback (same layout)
      us8 pk0, pk1;
      #pragma unroll
      for (int j=0;j<8;j++) pk0[j] = Sb[koff + (size_t)kk0*HW + p_lds[mm + j]];
      #pragma unroll
      for (int j=0;j<8;j++) pk1[j] = Sb[koff + (size_t)kk1*HW + p_lds[mm + j]];
      *(us8*)&stage[buf*4096 + w*1024 + l*8]       = pk0;
      *(us8*)&stage[buf*4096 + w*1024 + 512 + l*8] = pk1;
    }
    gload16(Bbase + koff + oe0, lB);
    gload16(Bbase + koff + oe1, lB + 512);
  };

  auto compute = [&](int buf){
    const uint32_t aaddr = sh_base + (uint32_t)buf*8192u + laneA;
    const uint32_t baddr = sh_base + 16384u + (uint32_t)buf*8192u + laneB;
    FragU A0,A1,A2,A3,B0,B1,B2,B3;
    A0.h[0]=tr_read<0>(aaddr);    A0.h[1]=tr_read<1024>(aaddr);
    A1.h[0]=tr_read<128>(aaddr);  A1.h[1]=tr_read<1152>(aaddr);
    A2.h[0]=tr_read<256>(aaddr);  A2.h[1]=tr_read<1280>(aaddr);
    A3.h[0]=tr_read<384>(aaddr);  A3.h[1]=tr_read<1408>(aaddr);
    B0.h[0]=tr_read<0>(baddr);    B0.h[1]=tr_read<1024>(baddr);
    B1.h[0]=tr_read<128>(baddr);  B1.h[1]=tr_read<1152>(baddr);
    B2.h[0]=tr_read<256>(baddr);  B2.h[1]=tr_read<1280>(baddr);
    B3.h[0]=tr_read<384>(baddr);  B3.h[1]=tr_read<1408>(baddr);
    asm volatile("s_waitcnt lgkmcnt(0)" ::: "memory");
    __builtin_amdgcn_sched_barrier(0);
    acc[0][0]=__builtin_amdgcn_mfma_f32_16x16x32_bf16(A0.v,B0.v,acc[0][0],0,0,0);
    acc[0][1]=__builtin_amdgcn_mfma_f32_16x16x32_bf16(A0.v,B1.v,acc[0][1],0,0,0);
    acc[0][2]=__builtin_amdgcn_mfma_f32_16x16x32_bf16(A0.v,B2.v,acc[0][2],0,0,0);
    acc[0][3]=__builtin_amdgcn_mfma_f32_16x16x32_bf16(A0.v,B3.v,acc[0][3],0,0,0);
    acc[1][0]=__builtin_amdgcn_mfma_f32_16x16x32_bf16(A1.v,B0.v,acc[1][0],0,0,0);
    acc[1][1]=__builtin_amdgcn_mfma_f32_16x16x32_bf16(A1.v,B1.v,acc[1][1],0,0,0);
    acc[1][2]=__builtin_amdgcn_mfma_f32_16x16x32_bf16(A1.v,B2.v,acc[1][2],0,0,0);
    acc[1][3]=__builtin_amdgcn_mfma_f32_16x16x32_bf16(A1.v,B3.v,acc[1][3],0,0,0);
    acc[2][0]=__builtin_amdgcn_mfma_f32_16x16x32_bf16(A2.v,B0.v,acc[2][0],0,0,0);
    acc[2][1]=__builtin_amdgcn_mfma_f32_16x16x32_bf16(A2.v,B1.v,acc[2][1],0,0,0);
    acc[2][2]=__builtin_amdgcn_mfma_f32_16x16x32_bf16(A2.v,B2.v,acc[2][2],0,0,0);
    acc[2][3]=__builtin_amdgcn_mfma_f32_16x16x32_bf16(A2.v,B3.v,acc[2][3],0,0,0);
    acc[3][0]=__builtin_amdgcn_mfma_f32_16x16x32_bf16(A3.v,B0.v,acc[3][0],0,0,0);
    acc[3][1]=__builtin_amdgcn_mfma_f32_16x16x32_bf16(A3.v,B1.v,acc[3][1],0,0,0);
    acc[3][2]=__builtin_amdgcn_mfma_f32_16x16x32_bf16(A3.v,B2.v,acc[3][2],0,0,0);
    acc[3][3]=__builtin_amdgcn_mfma_f32_16x16x32_bf16(A3.v,B3.v,acc[3][3],0,0,0);
  };

  // ---- main K loop: 32 tiles of BK=32, double-buffered ----
  stage_fn(0, 0);
  int buf = 0;
  if (fastA){
    // T4 pipelined loop: counted vmcnt, prefetch stays in flight across barriers.
    // Per iter: issue stage(kt+1) [4 loads]; wait oldest 4 (= tile kt); barrier;
    // compute (tr_read + lgkmcnt(0) + MFMA); barrier (all reads of buf done
    // before next iter's stage overwrites it).
    for (int kt = 0; kt < 32; ++kt){
      if (kt < 31){
        stage_fn(buf^1, kt+1);
        asm volatile("s_waitcnt vmcnt(4)" ::: "memory");
      } else {
        asm volatile("s_waitcnt vmcnt(0)" ::: "memory");
      }
      asm volatile("s_barrier" ::: "memory");
      __builtin_amdgcn_sched_barrier(0);
      compute(buf);
      asm volatile("s_barrier" ::: "memory");
      buf ^= 1;
    }
  } else {
    // correctness fallback (mixed ds_write/gload staging): full drain each step
    __syncthreads();
    for (int kt = 0; kt < 32; ++kt){
      if (kt < 31) stage_fn(buf^1, kt+1);
      compute(buf);
      __syncthreads();
      buf ^= 1;
    }
  }

  // ---- norms from precomputed snorm ----
  if (t < 128) nAs[t] = snorm[(size_t)b*HW + p_lds[t]];
  else         nBs[t-128] = snorm[(size_t)(BATCH + b)*HW + mbase + (t-128)];
  __syncthreads();

  // ---- epilogue: normalize, positive capture, per-row top3-min ----
  float rncol[4];
  #pragma unroll
  for (int nf=0;nf<4;nf++) rncol[nf] = nBs[wc*64 + nf*16 + (l&15)];

  #pragma unroll
  for (int mf=0; mf<4; ++mf){
    #pragma unroll
    for (int r=0; r<4; ++r){
      const int row_l = wr*64 + mf*16 + (l>>4)*4 + r;   // D: col=lane&15, row=(lane>>4)*4+reg
      const int n_g   = ni*128 + row_l;
      const float an  = nAs[row_l];
      const float v0 = acc[mf][0][r] / fmaxf(an*rncol[0], 1e-8f);
      const float v1 = acc[mf][1][r] / fmaxf(an*rncol[1], 1e-8f);
      const float v2 = acc[mf][2][r] / fmaxf(an*rncol[2], 1e-8f);
      const float v3 = acc[mf][3][r] / fmaxf(an*rncol[3], 1e-8f);

      const int* pp = posidx + (size_t)(b*NA + n_g)*3;
      const int q  = pp[2]*FWID + pp[1];
      const int ql = q - (mbase + wc*64);
      if (ql >= 0 && ql < 64 && (ql & 15) == (l & 15)){
        const int sel = ql >> 4;
        const float pv = sel==0 ? v0 : sel==1 ? v1 : sel==2 ? v2 : v3;
        wpos[b*NA + n_g] = pv;
      }

      float x=1e30f, y=1e30f, z=1e30f;
      ins3(x,y,z,v0); ins3(x,y,z,v1); ins3(x,y,z,v2); ins3(x,y,z,v3);
      #pragma unroll
      for (int m=1; m<16; m<<=1){
        const float ox = __shfl_xor(x, m);
        const float oy = __shfl_xor(y, m);
        const float oz = __shfl_xor(z, m);
        ins3(x,y,z,ox); ins3(x,y,z,oy); ins3(x,y,z,oz);
      }
      if ((l & 15) == 0){
        float* dst = wtop + ((size_t)(b*NA + n_g)*NCHUNK + (mi*2 + wc))*3;
        dst[0]=x; dst[1]=y; dst[2]=z;
      }
    }
  }
}

// ---------------------------------------------------------------------------
// v1 (verified) fused kernel — fallback when workspace is too small.
// ---------------------------------------------------------------------------
__global__ __launch_bounds__(256)
void fused_gemm_top3_v1(const float* __restrict__ sketch,
                        const float* __restrict__ refk,
                        const int*   __restrict__ anchor,
                        const int*   __restrict__ posidx,
                        float* __restrict__ wtop,
                        float* __restrict__ wpos)
{
  __shared__ union {
    unsigned short stage[16384];
    struct { float nA[16][128]; float nB[16][128]; } nrm;
  } sh;
  __shared__ int   p_lds[128];
  __shared__ float nA2[128], nB2[128];

  const int t = threadIdx.x;
  const uint32_t bid = blockIdx.x;
  const uint32_t L = (bid & 7u)*128u + (bid >> 3);
  const int b  = L >> 6;
  const int ni = (L >> 3) & 7;
  const int mi = L & 7;

  const float* Sb = sketch + (size_t)b*CDIM*HW;
  const float* Rb = refk   + (size_t)b*CDIM*HW;

  if (t < 128){
    const int n_g = ni*128 + t;
    const int* ap = anchor + (size_t)(b*NA + n_g)*3;
    p_lds[t] = ap[2]*FWID + ap[1];
  }
  __syncthreads();
  const int p0 = p_lds[0];
  int okf = 1;
  if (t < 128) okf = (p_lds[t] == p0 + t);
  const int contig = __syncthreads_and(okf);

  const int colg = (t & 15)*8;
  const int rowg = t >> 4;
  const int mbase = mi*128;

  const int l  = t & 63;
  const int w  = t >> 6;
  const int wr = w >> 1, wc = w & 1;
  const uint32_t sh_base = (uint32_t)(uintptr_t)&sh.stage[0];
  const uint32_t laneA = ((uint32_t)(l>>4))*2048u + (uint32_t)wr*512u + (uint32_t)(l&15)*8u;
  const uint32_t laneB = ((uint32_t)(l>>4))*2048u + (uint32_t)wc*512u + (uint32_t)(l&15)*8u;
  const int off0 = ((rowg>>2)*8 + (colg>>4))*64 + (rowg&3)*16 + (colg&15);

  f32x4 acc[4][4];
  #pragma unroll
  for (int i=0;i<4;i++){
    #pragma unroll
    for (int j=0;j<4;j++){ f32x4 z = {0.f,0.f,0.f,0.f}; acc[i][j] = z; }
  }

  float sqA[8] = {0,0,0,0,0,0,0,0};
  float sqB[8] = {0,0,0,0,0,0,0,0};
  f4 ra[4], rb[4];

  auto load_tile = [&](int kt){
    const int c0 = kt*32 + rowg;
    const float* SA = Sb + (size_t)c0*HW;
    const float* RB = Rb + (size_t)c0*HW + mbase + colg;
    if (contig){
      const float* pA = SA + p0 + colg;
      ra[0] = *(const f4*)(pA);
      ra[1] = *(const f4*)(pA + 4);
      ra[2] = *(const f4*)(pA + 16*HW);
      ra[3] = *(const f4*)(pA + 16*HW + 4);
    } else {
      float* raf = (float*)ra;
      #pragma unroll
      for (int i=0;i<8;i++){
        const int pc = p_lds[colg + i];
        raf[i]   = SA[pc];
        raf[8+i] = SA[16*HW + pc];
      }
    }
    rb[0] = *(const f4*)(RB);
    rb[1] = *(const f4*)(RB + 4);
    rb[2] = *(const f4*)(RB + 16*HW);
    rb[3] = *(const f4*)(RB + 16*HW + 4);
  };

  auto cvt_store = [&](int buf){
    const float* raf = (const float*)ra;
    const float* rbf = (const float*)rb;
    us8 pk;
    #pragma unroll
    for (int i=0;i<8;i++){
      __hip_bfloat16 h = __float2bfloat16(raf[i]);
      pk[i] = __builtin_bit_cast(unsigned short, h);
      const float g = __bfloat162float(h);
      sqA[i] = fmaf(g, g, sqA[i]);
    }
    *(us8*)&sh.stage[buf*4096 + off0] = pk;
    #pragma unroll
    for (int i=0;i<8;i++){
      __hip_bfloat16 h = __float2bfloat16(raf[8+i]);
      pk[i] = __builtin_bit_cast(unsigned short, h);
      const float g = __bfloat162float(h);
      sqA[i] = fmaf(g, g, sqA[i]);
    }
    *(us8*)&sh.stage[buf*4096 + off0 + 2048] = pk;
    #pragma unroll
    for (int i=0;i<8;i++){
      __hip_bfloat16 h = __float2bfloat16(rbf[i]);
      pk[i] = __builtin_bit_cast(unsigned short, h);
      const float g = __bfloat162float(h);
      sqB[i] = fmaf(g, g, sqB[i]);
    }
    *(us8*)&sh.stage[8192 + buf*4096 + off0] = pk;
    #pragma unroll
    for (int i=0;i<8;i++){
      __hip_bfloat16 h = __float2bfloat16(rbf[8+i]);
      pk[i] = __builtin_bit_cast(unsigned short, h);
      const float g = __bfloat162float(h);
      sqB[i] = fmaf(g, g, sqB[i]);
    }
    *(us8*)&sh.stage[8192 + buf*4096 + off0 + 2048] = pk;
  };

  auto compute = [&](int buf){
    const uint32_t aaddr = sh_base + (uint32_t)buf*8192u + laneA;
    const uint32_t baddr = sh_base + 16384u + (uint32_t)buf*8192u + laneB;
    FragU A0,A1,A2,A3,B0,B1,B2,B3;
    A0.h[0]=tr_read<0>(aaddr);    A0.h[1]=tr_read<1024>(aaddr);
    A1.h[0]=tr_read<128>(aaddr);  A1.h[1]=tr_read<1152>(aaddr);
    A2.h[0]=tr_read<256>(aaddr);  A2.h[1]=tr_read<1280>(aaddr);
    A3.h[0]=tr_read<384>(aaddr);  A3.h[1]=tr_read<1408>(aaddr);
    B0.h[0]=tr_read<0>(baddr);    B0.h[1]=tr_read<1024>(baddr);
    B1.h[0]=tr_read<128>(baddr);  B1.h[1]=tr_read<1152>(baddr);
    B2.h[0]=tr_read<256>(baddr);  B2.h[1]=tr_read<1280>(baddr);
    B3.h[0]=tr_read<384>(baddr);  B3.h[1]=tr_read<1408>(baddr);
    asm volatile("s_waitcnt lgkmcnt(0)" ::: "memory");
    __builtin_amdgcn_sched_barrier(0);
    acc[0][0]=__builtin_amdgcn_mfma_f32_16x16x32_bf16(A0.v,B0.v,acc[0][0],0,0,0);
    acc[0][1]=__builtin_amdgcn_mfma_f32_16x16x32_bf16(A0.v,B1.v,acc[0][1],0,0,0);
    acc[0][2]=__builtin_amdgcn_mfma_f32_16x16x32_bf16(A0.v,B2.v,acc[0][2],0,0,0);
    acc[0][3]=__builtin_amdgcn_mfma_f32_16x16x32_bf16(A0.v,B3.v,acc[0][3],0,0,0);
    acc[1][0]=__builtin_amdgcn_mfma_f32_16x16x32_bf16(A1.v,B0.v,acc[1][0],0,0,0);
    acc[1][1]=__builtin_amdgcn_mfma_f32_16x16x32_bf16(A1.v,B1.v,acc[1][1],0,0,0);
    acc[1][2]=__builtin_amdgcn_mfma_f32_16x16x32_bf16(A1.v,B2.v,acc[1][2],0,0,0);
    acc[1][3]=__builtin_amdgcn_mfma_f32_16x16x32_bf16(A1.v,B3.v,acc[1][3],0,0,0);
    acc[2][0]=__builtin_amdgcn_mfma_f32_16x16x32_bf16(A2.v,B0.v,acc[2][0],0,0,0);
    acc[2][1]=__builtin_amdgcn_mfma_f32_16x16x32_bf16(A2.v,B1.v,acc[2][1],0,0,0);
    acc[2][2]=__builtin_amdgcn_mfma_f32_16x16x32_bf16(A2.v,B2.v,acc[2][2],0,0,0);
    acc[2][3]=__builtin_amdgcn_mfma_f32_16x16x32_bf16(A2.v,B3.v,acc[2][3],0,0,0);
    acc[3][0]=__builtin_amdgcn_mfma_f32_16x16x32_bf16(A3.v,B0.v,acc[3][0],0,0,0);
    acc[3][1]=__builtin_amdgcn_mfma_f32_16x16x32_bf16(A3.v,B1.v,acc[3][1],0,0,0);
    acc[3][2]=__builtin_amdgcn_mfma_f32_16x16x32_bf16(A3.v,B2.v,acc[3][2],0,0,0);
    acc[3][3]=__builtin_amdgcn_mfma_f32_16x16x32_bf16(A3.v,B3.v,acc[3][3],0,0,0);
  };

  load_tile(0);
  cvt_store(0);
  __syncthreads();
  int buf = 0;
  for (int kt = 0; kt < 32; ++kt){
    if (kt < 31) load_tile(kt+1);
    compute(buf);
    if (kt < 31) cvt_store(buf^1);
    __syncthreads();
    buf ^= 1;
  }

  #pragma unroll
  for (int i=0;i<8;i++) sh.nrm.nA[rowg][colg+i] = sqA[i];
  #pragma unroll
  for (int i=0;i<8;i++) sh.nrm.nB[rowg][colg+i] = sqB[i];
  __syncthreads();
  if (t < 128){
    float s = 0.f;
    #pragma unroll
    for (int r=0;r<16;r++) s += sh.nrm.nA[r][t];
    nA2[t] = s;
  } else {
    const int c2 = t - 128;
    float s = 0.f;
    #pragma unroll
    for (int r=0;r<16;r++) s += sh.nrm.nB[r][c2];
    nB2[c2] = s;
  }
  __syncthreads();

  float rncol[4];
  #pragma unroll
  for (int nf=0;nf<4;nf++) rncol[nf] = sqrtf(nB2[wc*64 + nf*16 + (l&15)]);

  #pragma unroll
  for (int mf=0; mf<4; ++mf){
    #pragma unroll
    for (int r=0; r<4; ++r){
      const int row_l = wr*64 + mf*16 + (l>>4)*4 + r;
      const int n_g   = ni*128 + row_l;
      const float an  = sqrtf(nA2[row_l]);
      const float v0 = acc[mf][0][r] / fmaxf(an*rncol[0], 1e-8f);
      const float v1 = acc[mf][1][r] / fmaxf(an*rncol[1], 1e-8f);
      const float v2 = acc[mf][2][r] / fmaxf(an*rncol[2], 1e-8f);
      const float v3 = acc[mf][3][r] / fmaxf(an*rncol[3], 1e-8f);

      const int* pp = posidx + (size_t)(b*NA + n_g)*3;
      const int q  = pp[2]*FWID + pp[1];
      const int ql = q - (mbase + wc*64);
      if (ql >= 0 && ql < 64 && (ql & 15) == (l & 15)){
        const int sel = ql >> 4;
        const float pv = sel==0 ? v0 : sel==1 ? v1 : sel==2 ? v2 : v3;
        wpos[b*NA + n_g] = pv;
      }

      float x=1e30f, y=1e30f, z=1e30f;
      ins3(x,y,z,v0); ins3(x,y,z,v1); ins3(x,y,z,v2); ins3(x,y,z,v3);
      #pragma unroll
      for (int m=1; m<16; m<<=1){
        const float ox = __shfl_xor(x, m);
        const float oy = __shfl_xor(y, m);
        const float oz = __shfl_xor(z, m);
        ins3(x,y,z,ox); ins3(x,y,z,oy); ins3(x,y,z,oz);
      }
      if ((l & 15) == 0){
        float* dst = wtop + ((size_t)(b*NA + n_g)*NCHUNK + (mi*2 + wc))*3;
        dst[0]=x; dst[1]=y; dst[2]=z;
      }
    }
  }
}

// ---------------------------------------------------------------------------
__global__ __launch_bounds__(256)
void merge_top3(const float* __restrict__ wtop, const float* __restrict__ wpos,
                float* __restrict__ partial){
  __shared__ float red[256];
  const int id = blockIdx.x*256 + threadIdx.x;
  const float* src = wtop + (size_t)id*(NCHUNK*3);
  float x=1e30f, y=1e30f, z=1e30f;
  #pragma unroll
  for (int i=0;i<NCHUNK*3;i++) ins3(x,y,z, src[i]);
  const float loss = fmaxf((x+y+z) - wpos[id] + MARGIN, 0.0f);
  red[threadIdx.x] = loss;
  __syncthreads();
  for (int s=128; s>0; s>>=1){
    if (threadIdx.x < s) red[threadIdx.x] += red[threadIdx.x+s];
    __syncthreads();
  }
  if (threadIdx.x == 0) partial[blockIdx.x] = red[0];
}

__global__ void final_sum(const float* __restrict__ partial, float* __restrict__ out){
  float v = partial[threadIdx.x];
  #pragma unroll
  for (int off=32; off>0; off>>=1) v += __shfl_down(v, off);
  if (threadIdx.x == 0) out[0] = v / (1e-6f + (float)NTOT);
}

// ---------------------------------------------------------------------------
extern "C" void kernel_launch(void* const* d_in, const int* in_sizes, int n_in,
                              void* d_out, int out_size, void* d_ws, size_t ws_size,
                              hipStream_t stream){
  const float* sketch = (const float*)d_in[0];
  const float* refk   = (const float*)d_in[1];
  const int*   anchor = (const int*)d_in[2];
  const int*   posidx = (const int*)d_in[3];
  float* out = (float*)d_out;

  float* wtop    = (float*)d_ws;                       // NTOT*NCHUNK*3 floats
  float* wpos    = wtop + (size_t)NTOT*NCHUNK*3;       // NTOT floats
  float* partial = wpos + NTOT;                        // 64 floats (+pad)
  unsigned short* bfS = (unsigned short*)(partial + 256);
  unsigned short* bfR = bfS + (size_t)BATCH*CDIM*HW;
  float* pnorm = (float*)(bfR + (size_t)BATCH*CDIM*HW);   // 1024*1024 floats
  float* snorm = pnorm + (size_t)1024*1024;               // 32*1024 floats
  const size_t need = (size_t)((char*)(snorm + 32*1024) - (char*)d_ws);

  if (ws_size >= need){
    convert_norm<<<dim3(1024), dim3(256), 0, stream>>>(sketch, refk, bfS, bfR, pnorm);
    norm_reduce<<<dim3(32), dim3(256), 0, stream>>>(pnorm, snorm);
    fused_gemm_top3_v2<<<dim3(1024), dim3(256), 0, stream>>>(bfS, bfR, snorm, anchor, posidx, wtop, wpos);
  } else {
    fused_gemm_top3_v1<<<dim3(1024), dim3(256), 0, stream>>>(sketch, refk, anchor, posidx, wtop, wpos);
  }
  merge_top3<<<dim3(64), dim3(256), 0, stream>>>(wtop, wpos, partial);
  final_sum<<<dim3(1), dim3(64), 0, stream>>>(partial, out);
}